// Round 2
// baseline (2960.168 us; speedup 1.0000x reference)
//
#include <hip/hip_runtime.h>

#define N_ROWS 131072
#define DIM    128
#define QST    4
#define KC     1024
#define BM     128     // rows per workgroup
#define BK     16      // d-lines per B chunk
#define CCHUNK 128     // codes per code-chunk
#define NTH    256

typedef __attribute__((address_space(3))) void lds_void;
typedef const __attribute__((address_space(1))) void glb_void;

// Transpose codebooks -> ET[q][d][k]; precompute c[q][k] = ||E_k||^2 in fp64
__global__ void k_prep(const float* __restrict__ cb, float* __restrict__ ET,
                       double* __restrict__ cvec) {
  int gid = blockIdx.x * blockDim.x + threadIdx.x;
  if (gid >= QST * KC) return;
  int q = gid >> 10, k = gid & (KC - 1);
  const float* e = cb + ((size_t)q * KC + k) * DIM;
  double s = 0.0;
  for (int d = 0; d < DIM; d++) {
    float v = e[d];
    s = fma((double)v, (double)v, s);
    ET[((size_t)q * DIM + d) * KC + k] = v;
  }
  cvec[q * KC + k] = s;
}

__global__ __launch_bounds__(NTH, 2) void k_stage(
    int st, const float* __restrict__ rin, float* __restrict__ rout,
    const float* __restrict__ cb, const float* __restrict__ ET,
    const double* __restrict__ cvec, float* __restrict__ oidx,
    float* __restrict__ lpart)
{
  extern __shared__ float smem[];
  float* A = smem;            // [DIM][BM]  (transposed residual tile), 64 KB
  float* B = smem + DIM * BM; // [2][BK][CCHUNK], 16 KB
  const int tid = threadIdx.x;
  const int tx = tid & 15, ty = tid >> 4;
  const int lane = tid & 63, wv = tid >> 6;
  const size_t rowbase = (size_t)blockIdx.x * BM;

  // ---- A staging: read residual rows (natural layout), transpose into LDS
  {
    int row = tid >> 1, h = tid & 1;
    const float4* src = (const float4*)(rin + (rowbase + row) * DIM + h * 64);
    #pragma unroll
    for (int i = 0; i < 16; i++) {
      float4 v = src[i];
      int d0 = h * 64 + i * 4;
      A[(d0 + 0) * BM + row] = v.x;
      A[(d0 + 1) * BM + row] = v.y;
      A[(d0 + 2) * BM + row] = v.z;
      A[(d0 + 3) * BM + row] = v.w;
    }
  }

  const float*  ETq = ET + (size_t)st * DIM * KC;
  const double* cqd = cvec + st * KC;
  const float*  Eq  = cb + (size_t)st * KC * DIM;

  // stage one B chunk (16 d-lines x 128 codes) via global_load_lds (16B/lane)
  auto stageB = [&](int ch, int buf) {
    int cc = ch >> 3, dkc = ch & 7;
    #pragma unroll
    for (int i = 0; i < 2; i++) {
      int dl = wv * 4 + i * 2 + (lane >> 5);   // d-line 0..15 within chunk
      const float* src = ETq + (size_t)(dkc * BK + dl) * KC + cc * CCHUNK + (lane & 31) * 4;
      float* dst = B + buf * (BK * CCHUNK) + (wv * 4 + i * 2) * CCHUNK; // wave-uniform
      __builtin_amdgcn_global_load_lds((glb_void*)src, (lds_void*)dst, 16, 0, 0);
    }
  };

  double best[8];
  int bidx[8];
  #pragma unroll
  for (int i = 0; i < 8; i++) { best[i] = 1e300; bidx[i] = 0; }

  stageB(0, 0);
  __syncthreads();   // drains vmcnt+lgkmcnt: A-tile + first B chunk ready

  for (int cc = 0; cc < 8; cc++) {
    double acc[8][8];
    #pragma unroll
    for (int r = 0; r < 8; r++)
      #pragma unroll
      for (int j = 0; j < 8; j++) acc[r][j] = 0.0;

    for (int dkc = 0; dkc < 8; dkc++) {
      int ch = cc * 8 + dkc;
      int buf = ch & 1;
      if (ch + 1 < 64) stageB(ch + 1, buf ^ 1);   // prefetch next chunk
      const float* Bb = B + buf * (BK * CCHUNK);
      #pragma unroll
      for (int dk = 0; dk < BK; dk++) {
        const float* Arow = A + (dkc * BK + dk) * BM + ty * 8;
        float4 a0 = *(const float4*)(Arow);
        float4 a1 = *(const float4*)(Arow + 4);
        const float* Brow = Bb + dk * CCHUNK + tx * 4;
        float4 b0 = *(const float4*)(Brow);
        float4 b1 = *(const float4*)(Brow + 64);
        double av[8] = {(double)a0.x, (double)a0.y, (double)a0.z, (double)a0.w,
                        (double)a1.x, (double)a1.y, (double)a1.z, (double)a1.w};
        double bv[8] = {(double)b0.x, (double)b0.y, (double)b0.z, (double)b0.w,
                        (double)b1.x, (double)b1.y, (double)b1.z, (double)b1.w};
        #pragma unroll
        for (int r = 0; r < 8; r++)
          #pragma unroll
          for (int j = 0; j < 8; j++)
            acc[r][j] = fma(av[r], bv[j], acc[r][j]);
      }
      __syncthreads();  // implicit vmcnt(0): prefetch landed during compute
    }

    // ---- scores for this code-chunk; running per-row argmin (exact in fp64)
    double cvd[8];
    #pragma unroll
    for (int j = 0; j < 8; j++) {
      int code = cc * CCHUNK + ((j < 4) ? (tx * 4 + j) : (64 + tx * 4 + (j - 4)));
      cvd[j] = cqd[code];
    }
    #pragma unroll
    for (int r = 0; r < 8; r++) {
      #pragma unroll
      for (int j = 0; j < 8; j++) {
        double sc = fma(-2.0, acc[r][j], cvd[j]);
        int code = cc * CCHUNK + ((j < 4) ? (tx * 4 + j) : (64 + tx * 4 + (j - 4)));
        if (sc < best[r]) { best[r] = sc; bidx[r] = code; }  // strict <: first-min
      }
    }
  }

  // ---- cross-tx argmin reduce (16 threads share each row), tie -> lowest idx
  #pragma unroll
  for (int m = 1; m < 16; m <<= 1) {
    #pragma unroll
    for (int r = 0; r < 8; r++) {
      double ob = __shfl_xor(best[r], m, 64);
      int    oi = __shfl_xor(bidx[r], m, 64);
      if (ob < best[r] || (ob == best[r] && oi < bidx[r])) { best[r] = ob; bidx[r] = oi; }
    }
  }

  int* idxs = (int*)B;  // B no longer needed: reuse for per-row indices
  if (tx == 0) {
    #pragma unroll
    for (int r = 0; r < 8; r++) {
      int row = ty * 8 + r;
      idxs[row] = bidx[r];
      oidx[(rowbase + row) * 4 + st] = (float)bidx[r];
    }
  }
  __syncthreads();

  // ---- fused update: gather q = E[idx], r_new = r_old - q, loss += (q-r_old)^2
  {
    int row = tid >> 1, h = tid & 1;
    int kidx = idxs[row];
    const float4* e4 = (const float4*)(Eq + (size_t)kidx * DIM + h * 64);
    float4* ro = (float4*)(rout + (rowbase + row) * DIM + h * 64);
    float lsum = 0.f;
    #pragma unroll
    for (int i = 0; i < 16; i++) {
      float4 ev = e4[i];
      int d0 = h * 64 + i * 4;
      float r0 = A[(d0 + 0) * BM + row];
      float r1 = A[(d0 + 1) * BM + row];
      float r2 = A[(d0 + 2) * BM + row];
      float r3 = A[(d0 + 3) * BM + row];
      float d0v = r0 - ev.x, d1v = r1 - ev.y, d2v = r2 - ev.z, d3v = r3 - ev.w;
      lsum = fmaf(d0v, d0v, lsum);
      lsum = fmaf(d1v, d1v, lsum);
      lsum = fmaf(d2v, d2v, lsum);
      lsum = fmaf(d3v, d3v, lsum);
      ro[i] = make_float4(d0v, d1v, d2v, d3v);
    }
    #pragma unroll
    for (int m = 1; m < 64; m <<= 1) lsum += __shfl_xor(lsum, m, 64);
    float* red = B + 256;
    if (lane == 0) red[wv] = lsum;
    __syncthreads();
    if (tid == 0) lpart[st * (N_ROWS / BM) + blockIdx.x] = red[0] + red[1] + red[2] + red[3];
  }
}

// x_q = x - r, in place (r lives in the x_q region of d_out)
__global__ void k_xq(const float* __restrict__ x, float* __restrict__ xq) {
  size_t i = (size_t)blockIdx.x * blockDim.x + threadIdx.x;
  size_t stride = (size_t)gridDim.x * blockDim.x;
  const float4* x4 = (const float4*)x;
  float4* o4 = (float4*)xq;
  size_t n4 = (size_t)N_ROWS * DIM / 4;
  for (size_t k = i; k < n4; k += stride) {
    float4 a = x4[k], b = o4[k];
    o4[k] = make_float4(a.x - b.x, a.y - b.y, a.z - b.z, a.w - b.w);
  }
}

__global__ void k_loss(const float* __restrict__ part, float* __restrict__ o) {
  __shared__ float red[4];
  int tid = threadIdx.x;
  float s = 0.f;
  for (int i = tid; i < QST * (N_ROWS / BM); i += NTH) s += part[i];
  #pragma unroll
  for (int m = 1; m < 64; m <<= 1) s += __shfl_xor(s, m, 64);
  if ((tid & 63) == 0) red[tid >> 6] = s;
  __syncthreads();
  if (tid == 0)
    o[0] = (red[0] + red[1] + red[2] + red[3]) *
           (1.25f / ((float)QST * (float)N_ROWS * (float)DIM));
}

extern "C" void kernel_launch(void* const* d_in, const int* in_sizes, int n_in,
                              void* d_out, int out_size, void* d_ws, size_t ws_size,
                              hipStream_t stream) {
  const float* x  = (const float*)d_in[0];
  const float* cb = (const float*)d_in[1];
  float* out = (float*)d_out;
  float* ws  = (float*)d_ws;

  float*  r    = out;                                // residual lives in x_q region
  float*  ET   = ws;                                 // Q*D*K transposed codebook (2 MB)
  double* cvec = (double*)(ET + (size_t)QST * DIM * KC); // Q*K ||E||^2 (fp64)
  float*  part = (float*)(cvec + (size_t)QST * KC);  // Q*(N/BM) loss partials

  float* out_loss = out + (size_t)N_ROWS * DIM;
  float* out_idx  = out_loss + 1;

  static const size_t SMEM = (DIM * BM + 2 * BK * CCHUNK) * sizeof(float); // 80 KB
  hipFuncSetAttribute(reinterpret_cast<const void*>(k_stage),
                      hipFuncAttributeMaxDynamicSharedMemorySize, (int)SMEM);

  k_prep<<<(QST * KC + NTH - 1) / NTH, NTH, 0, stream>>>(cb, ET, cvec);

  for (int s = 0; s < QST; s++) {
    const float* rin = (s == 0) ? x : r;
    k_stage<<<N_ROWS / BM, NTH, SMEM, stream>>>(s, rin, r, cb, ET, cvec,
                                                out_idx, part);
  }

  k_xq<<<2048, NTH, 0, stream>>>(x, out);
  k_loss<<<1, NTH, 0, stream>>>(part, out_loss);
}

// Round 3
// 2785.446 us; speedup vs baseline: 1.0627x; 1.0627x over previous
//
#include <hip/hip_runtime.h>

#define N_ROWS 131072
#define DIM    128
#define QST    4
#define KC     1024
#define BM     128     // rows per workgroup
#define BK     16      // d-lines per B chunk
#define CCHUNK 128     // codes per code-chunk
#define NTH    256
#define EPS    4e-3f   // certified fp32 argmin margin (>=4x realistic worst-case err)
#define FLAGB  (1 << 16)

typedef __attribute__((address_space(3))) void lds_void;
typedef const __attribute__((address_space(1))) void glb_void;

// Transpose codebooks -> ET[q][d][k]; c[q][k] = ||E_k||^2 in fp64 + fp32 copy
__global__ void k_prep(const float* __restrict__ cb, float* __restrict__ ET,
                       double* __restrict__ cvec64, float* __restrict__ cvec32) {
  int gid = blockIdx.x * blockDim.x + threadIdx.x;
  if (gid >= QST * KC) return;
  int q = gid >> 10, k = gid & (KC - 1);
  const float* e = cb + ((size_t)q * KC + k) * DIM;
  double s = 0.0;
  for (int d = 0; d < DIM; d++) {
    float v = e[d];
    s = fma((double)v, (double)v, s);
    ET[((size_t)q * DIM + d) * KC + k] = v;
  }
  cvec64[q * KC + k] = s;
  cvec32[q * KC + k] = (float)s;
}

__global__ __launch_bounds__(NTH, 2) void k_stage(
    int st, const float* __restrict__ rin, float* __restrict__ rout,
    const float* __restrict__ cb, const float* __restrict__ ET,
    const double* __restrict__ cvec64, const float* __restrict__ cvec32,
    float* __restrict__ oidx, float* __restrict__ lpart)
{
  extern __shared__ float smem[];
  float* A = smem;            // [DIM][BM]  (transposed residual tile), 64 KB
  float* B = smem + DIM * BM; // [2][BK][CCHUNK], 16 KB
  const int tid = threadIdx.x;
  const int tx = tid & 15, ty = tid >> 4;
  const int lane = tid & 63, wv = tid >> 6;
  const size_t rowbase = (size_t)blockIdx.x * BM;

  // ---- A staging: read residual rows (natural layout), transpose into LDS
  {
    int row = tid >> 1, h = tid & 1;
    const float4* src = (const float4*)(rin + (rowbase + row) * DIM + h * 64);
    #pragma unroll
    for (int i = 0; i < 16; i++) {
      float4 v = src[i];
      int d0 = h * 64 + i * 4;
      A[(d0 + 0) * BM + row] = v.x;
      A[(d0 + 1) * BM + row] = v.y;
      A[(d0 + 2) * BM + row] = v.z;
      A[(d0 + 3) * BM + row] = v.w;
    }
  }

  const float*  ETq  = ET + (size_t)st * DIM * KC;
  const double* cq64 = cvec64 + st * KC;
  const float*  cq32 = cvec32 + st * KC;
  const float*  Eq   = cb + (size_t)st * KC * DIM;

  // stage one B chunk (16 d-lines x 128 codes) via global_load_lds (16B/lane)
  auto stageB = [&](int ch, int buf) {
    int cc = ch >> 3, dkc = ch & 7;
    #pragma unroll
    for (int i = 0; i < 2; i++) {
      int dl = wv * 4 + i * 2 + (lane >> 5);   // d-line 0..15 within chunk
      const float* src = ETq + (size_t)(dkc * BK + dl) * KC + cc * CCHUNK + (lane & 31) * 4;
      float* dst = B + buf * (BK * CCHUNK) + (wv * 4 + i * 2) * CCHUNK; // wave-uniform
      __builtin_amdgcn_global_load_lds((glb_void*)src, (lds_void*)dst, 16, 0, 0);
    }
  };

  float b1[8], b2[8];
  int   i1[8];
  #pragma unroll
  for (int i = 0; i < 8; i++) { b1[i] = 3.4e38f; b2[i] = 3.4e38f; i1[i] = 0; }

  stageB(0, 0);
  __syncthreads();   // drains vmcnt+lgkmcnt: A-tile + first B chunk ready

  for (int cc = 0; cc < 8; cc++) {
    float acc[8][8];
    #pragma unroll
    for (int r = 0; r < 8; r++)
      #pragma unroll
      for (int j = 0; j < 8; j++) acc[r][j] = 0.f;

    for (int dkc = 0; dkc < 8; dkc++) {
      int ch = cc * 8 + dkc;
      int buf = ch & 1;
      if (ch + 1 < 64) stageB(ch + 1, buf ^ 1);   // prefetch next chunk
      const float* Bb = B + buf * (BK * CCHUNK);
      #pragma unroll
      for (int dk = 0; dk < BK; dk++) {
        const float* Arow = A + (dkc * BK + dk) * BM + ty * 8;
        float4 a0 = *(const float4*)(Arow);
        float4 a1 = *(const float4*)(Arow + 4);
        const float* Brow = Bb + dk * CCHUNK + tx * 4;
        float4 b0 = *(const float4*)(Brow);
        float4 bb1 = *(const float4*)(Brow + 64);
        float av[8] = {a0.x, a0.y, a0.z, a0.w, a1.x, a1.y, a1.z, a1.w};
        float bv[8] = {b0.x, b0.y, b0.z, b0.w, bb1.x, bb1.y, bb1.z, bb1.w};
        #pragma unroll
        for (int r = 0; r < 8; r++)
          #pragma unroll
          for (int j = 0; j < 8; j++)
            acc[r][j] = fmaf(av[r], bv[j], acc[r][j]);
      }
      __syncthreads();  // implicit vmcnt(0): prefetch landed during compute
    }

    // ---- scores; per-row top-2 (thread-local codes)
    float4 c0 = *(const float4*)(cq32 + cc * CCHUNK + tx * 4);
    float4 c1 = *(const float4*)(cq32 + cc * CCHUNK + 64 + tx * 4);
    float cv[8] = {c0.x, c0.y, c0.z, c0.w, c1.x, c1.y, c1.z, c1.w};
    #pragma unroll
    for (int r = 0; r < 8; r++) {
      #pragma unroll
      for (int j = 0; j < 8; j++) {
        float sc = fmaf(-2.f, acc[r][j], cv[j]);
        int code = cc * CCHUNK + ((j < 4) ? (tx * 4 + j) : (64 + tx * 4 + (j - 4)));
        if (sc < b1[r]) { b2[r] = b1[r]; b1[r] = sc; i1[r] = code; }
        else            { b2[r] = fminf(b2[r], sc); }   // sc==b1 -> gap 0 -> rescue
      }
    }
  }

  // ---- cross-tx top-2 reduce (16 threads share each row)
  #pragma unroll
  for (int m = 1; m < 16; m <<= 1) {
    #pragma unroll
    for (int r = 0; r < 8; r++) {
      float ob1 = __shfl_xor(b1[r], m, 64);
      int   oi1 = __shfl_xor(i1[r], m, 64);
      float ob2 = __shfl_xor(b2[r], m, 64);
      bool take = (ob1 < b1[r]) || (ob1 == b1[r] && oi1 < i1[r]);
      float loser = take ? b1[r] : ob1;
      if (take) { b1[r] = ob1; i1[r] = oi1; }
      b2[r] = fminf(fminf(b2[r], ob2), loser);
    }
  }

  int* idxs = (int*)B;  // B no longer needed: reuse for per-row idx (+flag bit16)
  if (tx == 0) {
    #pragma unroll
    for (int r = 0; r < 8; r++) {
      int fl = (b2[r] - b1[r] <= EPS) ? FLAGB : 0;
      idxs[ty * 8 + r] = i1[r] | fl;
    }
  }
  __syncthreads();

  // ---- exact fp64 rescue for uncertain rows (rare)
  int pred = (tid < BM) ? (idxs[tid] & FLAGB) : 0;
  int cnt = __syncthreads_count(pred != 0);
  if (cnt > 0) {
    double* redd = (double*)(B + 256);
    int*    redi = (int*)(B + 272);
    for (int row = 0; row < BM; row++) {
      if (!(idxs[row] & FLAGB)) continue;          // uniform branch
      double dot[4] = {0.0, 0.0, 0.0, 0.0};
      for (int d = 0; d < DIM; d++) {
        double a = (double)A[d * BM + row];        // LDS broadcast
        #pragma unroll
        for (int c = 0; c < 4; c++)
          dot[c] = fma(a, (double)ETq[(size_t)d * KC + tid + c * 256], dot[c]);
      }
      double bs = 1e300; int bk = 0;
      #pragma unroll
      for (int c = 0; c < 4; c++) {
        int k = tid + c * 256;
        double s = fma(-2.0, dot[c], cq64[k]);
        if (s < bs || (s == bs && k < bk)) { bs = s; bk = k; }
      }
      #pragma unroll
      for (int m = 1; m < 64; m <<= 1) {
        double ob = __shfl_xor(bs, m, 64);
        int    ok = __shfl_xor(bk, m, 64);
        if (ob < bs || (ob == bs && ok < bk)) { bs = ob; bk = ok; }
      }
      if (lane == 0) { redd[wv] = bs; redi[wv] = bk; }
      __syncthreads();
      if (tid == 0) {
        double fb = redd[0]; int fk = redi[0];
        #pragma unroll
        for (int w = 1; w < 4; w++) {
          if (redd[w] < fb || (redd[w] == fb && redi[w] < fk)) { fb = redd[w]; fk = redi[w]; }
        }
        idxs[row] = fk;                            // flag cleared
      }
      __syncthreads();
    }
  }

  // ---- fused update: gather q = E[idx], r_new = r_old - q, loss += (q-r_old)^2
  {
    int row = tid >> 1, h = tid & 1;
    int kidx = idxs[row] & 1023;
    if (h == 0) oidx[(rowbase + row) * 4 + st] = (float)kidx;
    const float4* e4 = (const float4*)(Eq + (size_t)kidx * DIM + h * 64);
    float4* ro = (float4*)(rout + (rowbase + row) * DIM + h * 64);
    float lsum = 0.f;
    #pragma unroll
    for (int i = 0; i < 16; i++) {
      float4 ev = e4[i];
      int d0 = h * 64 + i * 4;
      float r0 = A[(d0 + 0) * BM + row];
      float r1 = A[(d0 + 1) * BM + row];
      float r2 = A[(d0 + 2) * BM + row];
      float r3 = A[(d0 + 3) * BM + row];
      float d0v = r0 - ev.x, d1v = r1 - ev.y, d2v = r2 - ev.z, d3v = r3 - ev.w;
      lsum = fmaf(d0v, d0v, lsum);
      lsum = fmaf(d1v, d1v, lsum);
      lsum = fmaf(d2v, d2v, lsum);
      lsum = fmaf(d3v, d3v, lsum);
      ro[i] = make_float4(d0v, d1v, d2v, d3v);
    }
    #pragma unroll
    for (int m = 1; m < 64; m <<= 1) lsum += __shfl_xor(lsum, m, 64);
    float* red = B + 320;
    if (lane == 0) red[wv] = lsum;
    __syncthreads();
    if (tid == 0) lpart[st * (N_ROWS / BM) + blockIdx.x] = red[0] + red[1] + red[2] + red[3];
  }
}

// x_q = x - r, in place (r lives in the x_q region of d_out)
__global__ void k_xq(const float* __restrict__ x, float* __restrict__ xq) {
  size_t i = (size_t)blockIdx.x * blockDim.x + threadIdx.x;
  size_t stride = (size_t)gridDim.x * blockDim.x;
  const float4* x4 = (const float4*)x;
  float4* o4 = (float4*)xq;
  size_t n4 = (size_t)N_ROWS * DIM / 4;
  for (size_t k = i; k < n4; k += stride) {
    float4 a = x4[k], b = o4[k];
    o4[k] = make_float4(a.x - b.x, a.y - b.y, a.z - b.z, a.w - b.w);
  }
}

__global__ void k_loss(const float* __restrict__ part, float* __restrict__ o) {
  __shared__ float red[4];
  int tid = threadIdx.x;
  float s = 0.f;
  for (int i = tid; i < QST * (N_ROWS / BM); i += NTH) s += part[i];
  #pragma unroll
  for (int m = 1; m < 64; m <<= 1) s += __shfl_xor(s, m, 64);
  if ((tid & 63) == 0) red[tid >> 6] = s;
  __syncthreads();
  if (tid == 0)
    o[0] = (red[0] + red[1] + red[2] + red[3]) *
           (1.25f / ((float)QST * (float)N_ROWS * (float)DIM));
}

extern "C" void kernel_launch(void* const* d_in, const int* in_sizes, int n_in,
                              void* d_out, int out_size, void* d_ws, size_t ws_size,
                              hipStream_t stream) {
  const float* x  = (const float*)d_in[0];
  const float* cb = (const float*)d_in[1];
  float* out = (float*)d_out;
  float* ws  = (float*)d_ws;

  float*  r      = out;                                   // residual in x_q region
  float*  ET     = ws;                                    // Q*D*K transposed (2 MB)
  double* cvec64 = (double*)(ET + (size_t)QST * DIM * KC);
  float*  cvec32 = (float*)(cvec64 + (size_t)QST * KC);
  float*  part   = cvec32 + (size_t)QST * KC;             // Q*(N/BM) loss partials

  float* out_loss = out + (size_t)N_ROWS * DIM;
  float* out_idx  = out_loss + 1;

  static const size_t SMEM = (DIM * BM + 2 * BK * CCHUNK) * sizeof(float); // 80 KB
  hipFuncSetAttribute(reinterpret_cast<const void*>(k_stage),
                      hipFuncAttributeMaxDynamicSharedMemorySize, (int)SMEM);

  k_prep<<<(QST * KC + NTH - 1) / NTH, NTH, 0, stream>>>(cb, ET, cvec64, cvec32);

  for (int s = 0; s < QST; s++) {
    const float* rin = (s == 0) ? x : r;
    k_stage<<<N_ROWS / BM, NTH, SMEM, stream>>>(s, rin, r, cb, ET, cvec64, cvec32,
                                                out_idx, part);
  }

  k_xq<<<2048, NTH, 0, stream>>>(x, out);
  k_loss<<<1, NTH, 0, stream>>>(part, out_loss);
}